// Round 2
// baseline (121.775 us; speedup 1.0000x reference)
//
#include <hip/hip_runtime.h>
#include <stdint.h>

// out[b,o] = x@W - 0.5*(||x_b||^2 + ||w_o||^2)
// x [2048][1024] f32, W [1024][4096] f32, out [2048][4096] f32
#define BATCH 2048
#define DIN   1024
#define DOUT  4096

// ---------- helpers ----------

// fp32 -> bf16 bits, round-to-nearest-even
__device__ __forceinline__ ushort f2bf(float f) {
    uint32_t u = __float_as_uint(f);
    u += 0x7fffu + ((u >> 16) & 1u);
    return (ushort)(u >> 16);
}

// async global->LDS, 16B/lane; LDS dest is wave-uniform base + lane*16 (m97/m104)
__device__ __forceinline__ void async_copy16(const void* gsrc, void* ldst) {
    __builtin_amdgcn_global_load_lds(
        reinterpret_cast<uint32_t __attribute__((address_space(1)))*>(
            reinterpret_cast<uintptr_t>(gsrc)),
        reinterpret_cast<uint32_t __attribute__((address_space(3)))*>(
            reinterpret_cast<uintptr_t>(ldst)),
        16, 0, 0);
}

typedef __bf16 bf16x8 __attribute__((ext_vector_type(8)));
typedef float  f32x4  __attribute__((ext_vector_type(4)));

// ---------- prep kernels ----------

// One block per row of x: cast to bf16 + fp32 row sum-of-squares.
__global__ __launch_bounds__(256) void prep_x(const float* __restrict__ x,
                                              ushort* __restrict__ xb,
                                              float* __restrict__ xsq) {
    const int row = blockIdx.x;
    const int t = threadIdx.x;
    const float4 v = *(const float4*)(x + (size_t)row * DIN + t * 4);
    ushort4 pk;
    pk.x = f2bf(v.x); pk.y = f2bf(v.y); pk.z = f2bf(v.z); pk.w = f2bf(v.w);
    *(ushort4*)(xb + (size_t)row * DIN + t * 4) = pk;

    float s = v.x * v.x + v.y * v.y + v.z * v.z + v.w * v.w;
    #pragma unroll
    for (int off = 32; off > 0; off >>= 1) s += __shfl_down(s, off);
    __shared__ float ws[4];
    if ((t & 63) == 0) ws[t >> 6] = s;
    __syncthreads();
    if (t == 0) xsq[row] = ws[0] + ws[1] + ws[2] + ws[3];
}

// Transpose W [DIN][DOUT] f32 -> wbt [DOUT][DIN] bf16 via LDS 64x64 tiles.
// Block (bx, jb): columns bx*64..+64, rows jb*256..+256 (4 sub-tiles).
// Writes K-partial column sums-of-squares to wsqp[jb*DOUT + col] (no atomics).
__global__ __launch_bounds__(256) void prep_w(const float* __restrict__ W,
                                              ushort* __restrict__ wbt,
                                              float* __restrict__ wsqp) {
    __shared__ float tile[64][65];  // +1 pad: conflict-free transposed read
    const int o0 = blockIdx.x * 64;
    const int jb = blockIdx.y;      // 0..3 K-chunk
    const int tx = threadIdx.x & 63;
    const int ty = threadIdx.x >> 6;

    float ssq = 0.f;
    for (int sub = 0; sub < 4; ++sub) {
        const int i0 = jb * 256 + sub * 64;
        if (sub) __syncthreads();
        #pragma unroll
        for (int r = ty; r < 64; r += 4) {        // coalesced read of W rows
            const float v = W[(size_t)(i0 + r) * DOUT + o0 + tx];
            tile[r][tx] = v;
            ssq += v * v;                          // partial for column o0+tx
        }
        __syncthreads();
        #pragma unroll
        for (int r = ty; r < 64; r += 4)           // coalesced write of W^T rows
            wbt[(size_t)(o0 + r) * DIN + i0 + tx] = f2bf(tile[tx][r]);
    }
    __syncthreads();
    tile[ty][tx] = ssq;                            // cross-wave reduce (4 partials)
    __syncthreads();
    if (ty == 0)
        wsqp[(size_t)jb * DOUT + o0 + tx] =
            tile[0][tx] + tile[1][tx] + tile[2][tx] + tile[3][tx];
}

// ---------- GEMM + epilogue ----------
// A = xb [BATCH][DIN] bf16, Bt = wbt [DOUT][DIN] bf16 (W^T), out fp32.
// 128x128 tile, BK=32, 4 waves (2x2), 4x4 16x16x32 MFMA per wave.
//
// LDS swizzle: within each 32-ushort row, the 4 k-chunks (8 ushorts each) are
// rotated by (tile_row>>1)&3. Fragment ds_read_b128 bank-group index becomes
// (4m + (c + m/2)&3) % 8 -> all 8 groups hit twice per quad = 2-way = free
// (vs 8-way = 2.94x for the unswizzled layout).
#define BM 128
#define BN 128
#define BK 32

__global__ __launch_bounds__(256, 2) void gemm_bt_epi(
    const ushort* __restrict__ A,
    const ushort* __restrict__ Bt,
    const float* __restrict__ xsq,
    const float* __restrict__ wsqp,
    float* __restrict__ out) {
    __shared__ __align__(16) ushort sA[BM * BK];  // 8 KiB
    __shared__ __align__(16) ushort sB[BN * BK];  // 8 KiB

    const int tid  = threadIdx.x;
    const int wv   = tid >> 6;
    const int lane = tid & 63;
    const int wr = wv >> 1, wc = wv & 1;
    const int m0 = blockIdx.y * BM;
    const int n0 = blockIdx.x * BN;

    // Staging: wave wv fills LDS bytes [wv*2048, +2048) as two 1024B insts.
    // Lane l, inst q: dest row = wv*32 + q*16 + l/4, position p = l&3.
    // Swizzle: stored chunk c = (p - row/2)&3 = ((l&3) - (l>>3)) & 3
    // (wv*16 and q*8 are ==0 mod 4, so c is lane-only and q-invariant).
    const int st_row = wv * 32 + (lane >> 2);
    const int st_col = (((lane & 3) - (lane >> 3)) & 3) * 8;

    const ushort* agp0 = A  + (size_t)(m0 + st_row)      * DIN + st_col;
    const ushort* agp1 = A  + (size_t)(m0 + st_row + 16) * DIN + st_col;
    const ushort* bgp0 = Bt + (size_t)(n0 + st_row)      * DIN + st_col;
    const ushort* bgp1 = Bt + (size_t)(n0 + st_row + 16) * DIN + st_col;

    ushort* sA0 = &sA[wv * 1024];
    ushort* sA1 = &sA[wv * 1024 + 512];
    ushort* sB0 = &sB[wv * 1024];
    ushort* sB1 = &sB[wv * 1024 + 512];

    f32x4 acc[4][4] = {};

    // Fragment reads: lane wants chunk c = lane>>4 of row m; it sits at
    // position p = (c + m/2)&3. With m = wr*64 + (lane&15) + i*16, the
    // multiples of 8 in m/2 vanish mod 4: p = ((lane>>4) + ((lane&15)>>1))&3,
    // constant across i and identical for A and B.
    const int a_row = wr * 64 + (lane & 15);
    const int b_row = wc * 64 + (lane & 15);
    const int kp    = ((((lane >> 4) + ((lane & 15) >> 1)) & 3)) * 8;

    for (int kt = 0; kt < DIN; kt += BK) {
        __syncthreads();
        async_copy16(agp0 + kt, sA0);
        async_copy16(agp1 + kt, sA1);
        async_copy16(bgp0 + kt, sB0);
        async_copy16(bgp1 + kt, sB1);
        __syncthreads();  // drains vmcnt: staging visible

        bf16x8 fa[4], fb[4];
        #pragma unroll
        for (int i = 0; i < 4; ++i)
            fa[i] = *(const bf16x8*)&sA[(a_row + i * 16) * BK + kp];
        #pragma unroll
        for (int i = 0; i < 4; ++i)
            fb[i] = *(const bf16x8*)&sB[(b_row + i * 16) * BK + kp];

        #pragma unroll
        for (int mi = 0; mi < 4; ++mi)
            #pragma unroll
            for (int ni = 0; ni < 4; ++ni)
                acc[mi][ni] = __builtin_amdgcn_mfma_f32_16x16x32_bf16(
                    fa[mi], fb[ni], acc[mi][ni], 0, 0, 0);
    }

    // Epilogue. C/D layout (m89/m91): col = lane&15, row = (lane>>4)*4 + r.
    const int er = (lane >> 4) * 4;
    const int ec = lane & 15;
    float wh[4];
    #pragma unroll
    for (int ni = 0; ni < 4; ++ni) {
        const int col = n0 + wc * 64 + ni * 16 + ec;
        wh[ni] = 0.5f * (wsqp[col] + wsqp[DOUT + col] +
                         wsqp[2 * DOUT + col] + wsqp[3 * DOUT + col]);
    }
    #pragma unroll
    for (int mi = 0; mi < 4; ++mi) {
        const int row = m0 + wr * 64 + mi * 16 + er;
        #pragma unroll
        for (int r = 0; r < 4; ++r) {
            const float xh = 0.5f * xsq[row + r];
            #pragma unroll
            for (int ni = 0; ni < 4; ++ni) {
                const int col = n0 + wc * 64 + ni * 16 + ec;
                out[(size_t)(row + r) * DOUT + col] = acc[mi][ni][r] - xh - wh[ni];
            }
        }
    }
}

// ---------- launch ----------

extern "C" void kernel_launch(void* const* d_in, const int* in_sizes, int n_in,
                              void* d_out, int out_size, void* d_ws, size_t ws_size,
                              hipStream_t stream) {
    const float* x = (const float*)d_in[0];
    const float* W = (const float*)d_in[1];
    float* out = (float*)d_out;

    // Workspace layout (~12.1 MiB):
    //   [0, 4MiB)          xb   : bf16 x   [2048][1024]
    //   [4MiB, 12MiB)      wbt  : bf16 W^T [4096][1024]
    //   [12MiB, +8KiB)     xsq  : f32 [2048]
    //   [12MiB+32KiB, +64KiB) wsqp : f32 [4][4096] K-partial col sums
    char* ws = (char*)d_ws;
    ushort* xb   = (ushort*)ws;
    ushort* wbt  = (ushort*)(ws + (4u << 20));
    float*  xsq  = (float*)(ws + (12u << 20));
    float*  wsqp = (float*)(ws + (12u << 20) + (32u << 10));

    prep_x<<<BATCH, 256, 0, stream>>>(x, xb, xsq);
    prep_w<<<dim3(DOUT / 64, 4), 256, 0, stream>>>(W, wbt, wsqp);
    gemm_bt_epi<<<dim3(DOUT / BN, BATCH / BM), 256, 0, stream>>>(xb, wbt, xsq, wsqp, out);
}

// Round 3
// 114.132 us; speedup vs baseline: 1.0670x; 1.0670x over previous
//
#include <hip/hip_runtime.h>
#include <stdint.h>

// out[b,o] = x@W - 0.5*(||x_b||^2 + ||w_o||^2)
// x [2048][1024] f32, W [1024][4096] f32, out [2048][4096] f32
#define BATCH 2048
#define DIN   1024
#define DOUT  4096

// ---------- helpers ----------

__device__ __forceinline__ ushort f2bf(float f) {
    uint32_t u = __float_as_uint(f);
    u += 0x7fffu + ((u >> 16) & 1u);
    return (ushort)(u >> 16);
}

// async global->LDS, 16B/lane; LDS dest is wave-uniform base + lane*16 (m97/m104)
__device__ __forceinline__ void async_copy16(const void* gsrc, void* ldst) {
    __builtin_amdgcn_global_load_lds(
        reinterpret_cast<uint32_t __attribute__((address_space(1)))*>(
            reinterpret_cast<uintptr_t>(gsrc)),
        reinterpret_cast<uint32_t __attribute__((address_space(3)))*>(
            reinterpret_cast<uintptr_t>(ldst)),
        16, 0, 0);
}

typedef __bf16 bf16x8 __attribute__((ext_vector_type(8)));
typedef float  f32x4  __attribute__((ext_vector_type(4)));

// ---------- fused prep (one dispatch) ----------
// Blocks [0,256): transpose W chunk -> wbt bf16 + K-partial col sums wsqp.
// Blocks [256,384): cast x -> bf16 + row sums xsq (wave-per-row, 4 rows/wave).
__global__ __launch_bounds__(256) void prep_fused(const float* __restrict__ x,
                                                  const float* __restrict__ W,
                                                  ushort* __restrict__ xb,
                                                  float* __restrict__ xsq,
                                                  ushort* __restrict__ wbt,
                                                  float* __restrict__ wsqp) {
    __shared__ float tile[64][65];
    const int b = blockIdx.x;
    if (b < 256) {
        const int o0 = (b >> 2) * 64;
        const int jb = b & 3;  // K-chunk 0..3
        const int tx = threadIdx.x & 63;
        const int ty = threadIdx.x >> 6;
        float ssq = 0.f;
        for (int sub = 0; sub < 4; ++sub) {
            const int i0 = jb * 256 + sub * 64;
            if (sub) __syncthreads();
            #pragma unroll
            for (int r = ty; r < 64; r += 4) {
                const float v = W[(size_t)(i0 + r) * DOUT + o0 + tx];
                tile[r][tx] = v;
                ssq += v * v;
            }
            __syncthreads();
            #pragma unroll
            for (int r = ty; r < 64; r += 4)
                wbt[(size_t)(o0 + r) * DIN + i0 + tx] = f2bf(tile[tx][r]);
        }
        __syncthreads();
        tile[ty][tx] = ssq;
        __syncthreads();
        if (ty == 0)
            wsqp[(size_t)jb * DOUT + o0 + tx] =
                tile[0][tx] + tile[1][tx] + tile[2][tx] + tile[3][tx];
    } else {
        const int blk  = b - 256;             // 0..127, 16 rows each
        const int wv   = threadIdx.x >> 6;
        const int lane = threadIdx.x & 63;
        #pragma unroll
        for (int rr = 0; rr < 4; ++rr) {
            const int row = blk * 16 + wv * 4 + rr;
            const float4* src = (const float4*)(x + (size_t)row * DIN);
            ushort4* dst = (ushort4*)(xb + (size_t)row * DIN);
            float s = 0.f;
            #pragma unroll
            for (int c = 0; c < 4; ++c) {
                const float4 v = src[c * 64 + lane];
                ushort4 pk;
                pk.x = f2bf(v.x); pk.y = f2bf(v.y);
                pk.z = f2bf(v.z); pk.w = f2bf(v.w);
                dst[c * 64 + lane] = pk;
                s += v.x * v.x + v.y * v.y + v.z * v.z + v.w * v.w;
            }
            #pragma unroll
            for (int off = 32; off > 0; off >>= 1) s += __shfl_down(s, off);
            if (lane == 0) xsq[row] = s;
        }
    }
}

// ---------- GEMM + epilogue ----------
// A = xb [BATCH][DIN] bf16, Bt = wbt [DOUT][DIN] bf16, out fp32.
// 128x128 tile, BK=64 (16 barrier pairs instead of 32), 4 waves (2x2),
// 4x4 16x16x32 MFMA per wave per 32-k window (2 windows/iter).
//
// LDS rows are 128 B = 8 x 16B chunks. Swizzle: chunk stored at position
// p = (c + row) & 7. Row stride is a whole bank wrap (128 B), so the
// ds_read_b128 bank-group = p; within any 16-lane quad all 8 groups are hit
// exactly twice -> 2-way = free. Staging permutes chunks inside each 128 B
// row -> coalescing unchanged.
#define BM 128
#define BN 128
#define BK 64

__global__ __launch_bounds__(256, 2) void gemm_bt_epi(
    const ushort* __restrict__ A,
    const ushort* __restrict__ Bt,
    const float* __restrict__ xsq,
    const float* __restrict__ wsqp,
    float* __restrict__ out) {
    __shared__ __align__(16) ushort sA[BM * BK];  // 16 KiB
    __shared__ __align__(16) ushort sB[BN * BK];  // 16 KiB

    const int tid  = threadIdx.x;
    const int wv   = tid >> 6;
    const int lane = tid & 63;
    const int wr = wv >> 1, wc = wv & 1;
    const int m0 = blockIdx.y * BM;
    const int n0 = blockIdx.x * BN;

    // Staging: wave wv fills tile rows [wv*32, wv*32+32), 4 insts of 1 KiB per
    // operand. Inst q: lane l -> row wv*32 + q*8 + (l>>3), stored pos l&7,
    // global chunk c = ((l&7) - (l>>3)) & 7  (row&7 == l>>3 for all q).
    const int st_row = wv * 32 + (lane >> 3);
    const int st_c   = ((((lane & 7) - (lane >> 3)) & 7)) * 8;

    const ushort* agp = A  + (size_t)(m0 + st_row) * DIN + st_c;
    const ushort* bgp = Bt + (size_t)(n0 + st_row) * DIN + st_c;

    f32x4 acc[4][4] = {};

    // Fragment geometry: row m = base + (lane&15) + i*16; wanted chunk for
    // 32-k window kk is c = (lane>>4) + 4*kk, stored at p = (c + (lane&7))&7.
    const int a_row = wr * 64 + (lane & 15);
    const int b_row = wc * 64 + (lane & 15);
    int kpos[2];
    #pragma unroll
    for (int kk = 0; kk < 2; ++kk)
        kpos[kk] = ((((lane >> 4) + 4 * kk + (lane & 7)) & 7)) * 8;

    for (int kt = 0; kt < DIN; kt += BK) {
        __syncthreads();
        #pragma unroll
        for (int q = 0; q < 4; ++q)
            async_copy16(agp + (size_t)q * 8 * DIN + kt, &sA[wv * 2048 + q * 512]);
        #pragma unroll
        for (int q = 0; q < 4; ++q)
            async_copy16(bgp + (size_t)q * 8 * DIN + kt, &sB[wv * 2048 + q * 512]);
        __syncthreads();  // drains vmcnt: staged tile visible

        #pragma unroll
        for (int kk = 0; kk < 2; ++kk) {
            bf16x8 fa[4], fb[4];
            #pragma unroll
            for (int i = 0; i < 4; ++i)
                fa[i] = *(const bf16x8*)&sA[(a_row + i * 16) * BK + kpos[kk]];
            #pragma unroll
            for (int i = 0; i < 4; ++i)
                fb[i] = *(const bf16x8*)&sB[(b_row + i * 16) * BK + kpos[kk]];
            #pragma unroll
            for (int mi = 0; mi < 4; ++mi)
                #pragma unroll
                for (int ni = 0; ni < 4; ++ni)
                    acc[mi][ni] = __builtin_amdgcn_mfma_f32_16x16x32_bf16(
                        fa[mi], fb[ni], acc[mi][ni], 0, 0, 0);
        }
    }

    // Epilogue. C/D layout (m89/m91): col = lane&15, row = (lane>>4)*4 + r.
    const int er = (lane >> 4) * 4;
    const int ec = lane & 15;
    float wh[4];
    #pragma unroll
    for (int ni = 0; ni < 4; ++ni) {
        const int col = n0 + wc * 64 + ni * 16 + ec;
        wh[ni] = 0.5f * (wsqp[col] + wsqp[DOUT + col] +
                         wsqp[2 * DOUT + col] + wsqp[3 * DOUT + col]);
    }
    #pragma unroll
    for (int mi = 0; mi < 4; ++mi) {
        const int row = m0 + wr * 64 + mi * 16 + er;
        #pragma unroll
        for (int r = 0; r < 4; ++r) {
            const float xh = 0.5f * xsq[row + r];
            #pragma unroll
            for (int ni = 0; ni < 4; ++ni) {
                const int col = n0 + wc * 64 + ni * 16 + ec;
                out[(size_t)(row + r) * DOUT + col] = acc[mi][ni][r] - xh - wh[ni];
            }
        }
    }
}

// ---------- launch ----------

extern "C" void kernel_launch(void* const* d_in, const int* in_sizes, int n_in,
                              void* d_out, int out_size, void* d_ws, size_t ws_size,
                              hipStream_t stream) {
    const float* x = (const float*)d_in[0];
    const float* W = (const float*)d_in[1];
    float* out = (float*)d_out;

    // Workspace layout (~12.1 MiB):
    //   [0, 4MiB)             xb   : bf16 x   [2048][1024]
    //   [4MiB, 12MiB)         wbt  : bf16 W^T [4096][1024]
    //   [12MiB, +8KiB)        xsq  : f32 [2048]
    //   [12MiB+32KiB, +64KiB) wsqp : f32 [4][4096] K-partial col sums
    char* ws = (char*)d_ws;
    ushort* xb   = (ushort*)ws;
    ushort* wbt  = (ushort*)(ws + (4u << 20));
    float*  xsq  = (float*)(ws + (12u << 20));
    float*  wsqp = (float*)(ws + (12u << 20) + (32u << 10));

    prep_fused<<<384, 256, 0, stream>>>(x, W, xb, xsq, wbt, wsqp);
    gemm_bt_epi<<<dim3(DOUT / BN, BATCH / BM), 256, 0, stream>>>(xb, wbt, xsq, wsqp, out);
}

// Round 4
// 113.881 us; speedup vs baseline: 1.0693x; 1.0022x over previous
//
#include <hip/hip_runtime.h>
#include <stdint.h>

// out[b,o] = x@W - 0.5*(||x_b||^2 + ||w_o||^2)
// x [2048][1024] f32, W [1024][4096] f32, out [2048][4096] f32
#define BATCH 2048
#define DIN   1024
#define DOUT  4096

// ---------- helpers ----------

__device__ __forceinline__ ushort f2bf(float f) {
    uint32_t u = __float_as_uint(f);
    u += 0x7fffu + ((u >> 16) & 1u);
    return (ushort)(u >> 16);
}

// async global->LDS, 16B/lane; LDS dest is wave-uniform base + lane*16 (m97/m104)
__device__ __forceinline__ void async_copy16(const void* gsrc, void* ldst) {
    __builtin_amdgcn_global_load_lds(
        reinterpret_cast<uint32_t __attribute__((address_space(1)))*>(
            reinterpret_cast<uintptr_t>(gsrc)),
        reinterpret_cast<uint32_t __attribute__((address_space(3)))*>(
            reinterpret_cast<uintptr_t>(ldst)),
        16, 0, 0);
}

typedef __bf16 bf16x8 __attribute__((ext_vector_type(8)));
typedef float  f32x4  __attribute__((ext_vector_type(4)));

// ---------- fused prep (one dispatch) ----------
// Blocks [0,256): transpose W chunk -> wbt bf16 + K-partial col sums wsqp.
// Blocks [256,384): cast x -> bf16 + row sums xsq (wave-per-row, 4 rows/wave).
__global__ __launch_bounds__(256) void prep_fused(const float* __restrict__ x,
                                                  const float* __restrict__ W,
                                                  ushort* __restrict__ xb,
                                                  float* __restrict__ xsq,
                                                  ushort* __restrict__ wbt,
                                                  float* __restrict__ wsqp) {
    __shared__ float tile[64][65];
    const int b = blockIdx.x;
    if (b < 256) {
        const int o0 = (b >> 2) * 64;
        const int jb = b & 3;  // K-chunk 0..3
        const int tx = threadIdx.x & 63;
        const int ty = threadIdx.x >> 6;
        float ssq = 0.f;
        for (int sub = 0; sub < 4; ++sub) {
            const int i0 = jb * 256 + sub * 64;
            if (sub) __syncthreads();
            #pragma unroll
            for (int r = ty; r < 64; r += 4) {
                const float v = W[(size_t)(i0 + r) * DOUT + o0 + tx];
                tile[r][tx] = v;
                ssq += v * v;
            }
            __syncthreads();
            #pragma unroll
            for (int r = ty; r < 64; r += 4)
                wbt[(size_t)(o0 + r) * DIN + i0 + tx] = f2bf(tile[tx][r]);
        }
        __syncthreads();
        tile[ty][tx] = ssq;
        __syncthreads();
        if (ty == 0)
            wsqp[(size_t)jb * DOUT + o0 + tx] =
                tile[0][tx] + tile[1][tx] + tile[2][tx] + tile[3][tx];
    } else {
        const int blk  = b - 256;             // 0..127, 16 rows each
        const int wv   = threadIdx.x >> 6;
        const int lane = threadIdx.x & 63;
        #pragma unroll
        for (int rr = 0; rr < 4; ++rr) {
            const int row = blk * 16 + wv * 4 + rr;
            const float4* src = (const float4*)(x + (size_t)row * DIN);
            ushort4* dst = (ushort4*)(xb + (size_t)row * DIN);
            float s = 0.f;
            #pragma unroll
            for (int c = 0; c < 4; ++c) {
                const float4 v = src[c * 64 + lane];
                ushort4 pk;
                pk.x = f2bf(v.x); pk.y = f2bf(v.y);
                pk.z = f2bf(v.z); pk.w = f2bf(v.w);
                dst[c * 64 + lane] = pk;
                s += v.x * v.x + v.y * v.y + v.z * v.z + v.w * v.w;
            }
            #pragma unroll
            for (int off = 32; off > 0; off >>= 1) s += __shfl_down(s, off);
            if (lane == 0) xsq[row] = s;
        }
    }
}

// ---------- GEMM + epilogue ----------
// A = xb [BATCH][DIN] bf16, Bt = wbt [DOUT][DIN] bf16, out fp32.
// 128x128 tile, BK=64, 4 waves (2x2), 4x4 16x16x32 MFMA per 32-k window.
//
// XCD swizzle: dispatcher assigns blockIdx%8 -> XCD round-robin. Decode so
// XCD x owns n-blocks [4x, 4x+4) for all m-blocks: its B-stripe is
// 512 cols x 2 KiB = 1 MiB -> L2-resident; the 4 co-resident n-blocks per
// m-block share each A-tile fetch through L2. Cuts L3-level read traffic
// ~256 MiB -> ~50 MiB.
//
// LDS swizzle (per 128 B row, 8 x 16B chunks): chunk c stored at position
// (c + row) & 7 -> ds_read_b128 hits all 8 bank-groups 2-way = free.
#define BM 128
#define BN 128
#define BK 64

__global__ __launch_bounds__(256, 2) void gemm_bt_epi(
    const ushort* __restrict__ A,
    const ushort* __restrict__ Bt,
    const float* __restrict__ xsq,
    const float* __restrict__ wsqp,
    float* __restrict__ out) {
    __shared__ __align__(16) ushort sA[BM * BK];  // 16 KiB
    __shared__ __align__(16) ushort sB[BN * BK];  // 16 KiB

    const int tid  = threadIdx.x;
    const int wv   = tid >> 6;
    const int lane = tid & 63;
    const int wr = wv >> 1, wc = wv & 1;

    // XCD-aware decode (bijective on 512 blocks)
    const int bid  = blockIdx.x;
    const int xcd  = bid & 7;
    const int slot = bid >> 3;          // 0..63
    const int nb   = xcd * 4 + (slot & 3);
    const int mb   = slot >> 2;         // 0..15
    const int m0 = mb * BM;
    const int n0 = nb * BN;

    // Staging: wave wv fills tile rows [wv*32, wv*32+32), 4 insts of 1 KiB per
    // operand. Inst q: lane l -> row wv*32 + q*8 + (l>>3), stored pos l&7,
    // global chunk c = ((l&7) - (l>>3)) & 7.
    const int st_row = wv * 32 + (lane >> 3);
    const int st_c   = ((((lane & 7) - (lane >> 3)) & 7)) * 8;

    const ushort* agp = A  + (size_t)(m0 + st_row) * DIN + st_c;
    const ushort* bgp = Bt + (size_t)(n0 + st_row) * DIN + st_c;

    f32x4 acc[4][4] = {};

    // Fragment geometry: row m = base + (lane&15) + i*16; wanted chunk for
    // 32-k window kk is c = (lane>>4) + 4*kk, stored at p = (c + (lane&7))&7.
    const int a_row = wr * 64 + (lane & 15);
    const int b_row = wc * 64 + (lane & 15);
    int kpos[2];
    #pragma unroll
    for (int kk = 0; kk < 2; ++kk)
        kpos[kk] = ((((lane >> 4) + 4 * kk + (lane & 7)) & 7)) * 8;

    for (int kt = 0; kt < DIN; kt += BK) {
        __syncthreads();
        #pragma unroll
        for (int q = 0; q < 4; ++q)
            async_copy16(agp + (size_t)q * 8 * DIN + kt, &sA[wv * 2048 + q * 512]);
        #pragma unroll
        for (int q = 0; q < 4; ++q)
            async_copy16(bgp + (size_t)q * 8 * DIN + kt, &sB[wv * 2048 + q * 512]);
        __syncthreads();  // drains vmcnt: staged tile visible

        #pragma unroll
        for (int kk = 0; kk < 2; ++kk) {
            bf16x8 fa[4], fb[4];
            #pragma unroll
            for (int i = 0; i < 4; ++i)
                fa[i] = *(const bf16x8*)&sA[(a_row + i * 16) * BK + kpos[kk]];
            #pragma unroll
            for (int i = 0; i < 4; ++i)
                fb[i] = *(const bf16x8*)&sB[(b_row + i * 16) * BK + kpos[kk]];
            #pragma unroll
            for (int mi = 0; mi < 4; ++mi)
                #pragma unroll
                for (int ni = 0; ni < 4; ++ni)
                    acc[mi][ni] = __builtin_amdgcn_mfma_f32_16x16x32_bf16(
                        fa[mi], fb[ni], acc[mi][ni], 0, 0, 0);
        }
    }

    // Epilogue. C/D layout (m89/m91): col = lane&15, row = (lane>>4)*4 + r.
    const int er = (lane >> 4) * 4;
    const int ec = lane & 15;
    float wh[4];
    #pragma unroll
    for (int ni = 0; ni < 4; ++ni) {
        const int col = n0 + wc * 64 + ni * 16 + ec;
        wh[ni] = 0.5f * (wsqp[col] + wsqp[DOUT + col] +
                         wsqp[2 * DOUT + col] + wsqp[3 * DOUT + col]);
    }
    #pragma unroll
    for (int mi = 0; mi < 4; ++mi) {
        const int row = m0 + wr * 64 + mi * 16 + er;
        #pragma unroll
        for (int r = 0; r < 4; ++r) {
            const float xh = 0.5f * xsq[row + r];
            #pragma unroll
            for (int ni = 0; ni < 4; ++ni) {
                const int col = n0 + wc * 64 + ni * 16 + ec;
                out[(size_t)(row + r) * DOUT + col] = acc[mi][ni][r] - xh - wh[ni];
            }
        }
    }
}

// ---------- launch ----------

extern "C" void kernel_launch(void* const* d_in, const int* in_sizes, int n_in,
                              void* d_out, int out_size, void* d_ws, size_t ws_size,
                              hipStream_t stream) {
    const float* x = (const float*)d_in[0];
    const float* W = (const float*)d_in[1];
    float* out = (float*)d_out;

    // Workspace layout (~12.1 MiB):
    //   [0, 4MiB)             xb   : bf16 x   [2048][1024]
    //   [4MiB, 12MiB)         wbt  : bf16 W^T [4096][1024]
    //   [12MiB, +8KiB)        xsq  : f32 [2048]
    //   [12MiB+32KiB, +64KiB) wsqp : f32 [4][4096] K-partial col sums
    char* ws = (char*)d_ws;
    ushort* xb   = (ushort*)ws;
    ushort* wbt  = (ushort*)(ws + (4u << 20));
    float*  xsq  = (float*)(ws + (12u << 20));
    float*  wsqp = (float*)(ws + (12u << 20) + (32u << 10));

    prep_fused<<<384, 256, 0, stream>>>(x, W, xb, xsq, wbt, wsqp);
    gemm_bt_epi<<<512, 256, 0, stream>>>(xb, wbt, xsq, wsqp, out);
}